// Round 7
// baseline (210.208 us; speedup 1.0000x reference)
//
#include <hip/hip_runtime.h>
#include <hip/hip_bf16.h>
#include <math.h>

#define NHEADS 16
#define DHEAD  64
#define CHDIM  80
#define RQn    6
#define RKn    2
#define RVn    2
#define BB     2
#define TT     2048
#define DDim   1024
#define NQK    800   // 480 + 320 combined projection rows

using frag16 = __attribute__((ext_vector_type(8))) short;   // 8 bf16 (4 VGPR)
using f32x4  = __attribute__((ext_vector_type(4))) float;   // 4 fp32 acc
using f32x16 = __attribute__((ext_vector_type(16))) float;  // 32x32 acc
using uint2v = __attribute__((ext_vector_type(2))) unsigned int;

#define AS1(p) ((const __attribute__((address_space(1))) unsigned int*)(p))
#define AS3(p) ((__attribute__((address_space(3))) unsigned int*)(p))

static __device__ __forceinline__ unsigned short bf16_bits(float f) {
    __hip_bfloat16 h = __float2bfloat16(f);
    return *(unsigned short*)&h;
}
static __device__ __forceinline__ unsigned int pk2(float a, float b) {
    return ((unsigned int)bf16_bits(b) << 16) | (unsigned int)bf16_bits(a);
}
static __device__ __forceinline__ float bfu2f(unsigned short u) {
    return __uint_as_float(((unsigned int)u) << 16);
}
// HW exp2 via the proper intrinsic (hazard-safe). log2(e) folded into q-scale.
static __device__ __forceinline__ float exp2_hw(float x) {
    return __builtin_amdgcn_exp2f(x);
}

// ---------------- fused fp32 -> bf16 convert (4 segments, 1 launch) ----------
__global__ __launch_bounds__(256) void cvt_all(
    const float* __restrict__ x, const float* __restrict__ wq,
    const float* __restrict__ wk, const float* __restrict__ wo,
    __hip_bfloat16* __restrict__ xb, __hip_bfloat16* __restrict__ wqk,
    __hip_bfloat16* __restrict__ wob)
{
    int bid = blockIdx.x;
    const float* src; __hip_bfloat16* dst; int n4;
    if (bid < 4096)      { src = x;  dst = xb;            n4 = 1048576; }
    else if (bid < 4576) { bid -= 4096; src = wq; dst = wqk;           n4 = 122880; }
    else if (bid < 4896) { bid -= 4576; src = wk; dst = wqk + 491520;  n4 = 81920; }
    else                 { bid -= 4896; src = wo; dst = wob;           n4 = 262144; }
    int i = bid * 256 + threadIdx.x;
    if (i < n4) {
        float4 v = *(const float4*)&src[i * 4];
        ushort4 o;
        o.x = bf16_bits(v.x); o.y = bf16_bits(v.y);
        o.z = bf16_bits(v.z); o.w = bf16_bits(v.w);
        *(ushort4*)&dst[i * 4] = o;
    }
}

// ---------- GEMM: C[M,N] = A[M,K]_bf16 * W[N,K]_bf16^T, 64x128 tile ---------
// BF16OUT: write bf16 C (used for abqkv to halve the round-trip traffic).
template <bool BF16OUT>
__global__ __launch_bounds__(256) void gemm_bf16(
    const __hip_bfloat16* __restrict__ A, const __hip_bfloat16* __restrict__ W,
    void* __restrict__ Cv, int M, int N, int K)
{
    __shared__ __hip_bfloat16 Asl[2][64 * 64];
    __shared__ __hip_bfloat16 Bsl[2][128 * 64];
    const int tid = threadIdx.x;
    const int w = tid >> 6, lane = tid & 63;
    const int l16 = lane & 15, quad = lane >> 4;
    const int bm = blockIdx.y * 64, bn = blockIdx.x * 128;

    // staging geometry
    int rSA[2], cSA[2];
    #pragma unroll
    for (int j = 0; j < 2; j++) {
        int L = (w * 2 + j) * 64 + lane;
        rSA[j] = L >> 3;
        cSA[j] = (L & 7) ^ (rSA[j] & 7);
    }
    int rSB[4], cSB[4];
    #pragma unroll
    for (int j = 0; j < 4; j++) {
        int L = (w * 4 + j) * 64 + lane;
        int r = L >> 3;
        cSB[j] = (L & 7) ^ (r & 7);
        int rb = bn + r;
        rSB[j] = (rb < N) ? rb : (N - 1);
    }

    f32x4 acc[4][2];
    #pragma unroll
    for (int mt = 0; mt < 4; mt++)
        #pragma unroll
        for (int nt = 0; nt < 2; nt++)
            acc[mt][nt] = (f32x4){0.f, 0.f, 0.f, 0.f};

    const int nK = K >> 6;
    #pragma unroll
    for (int j = 0; j < 2; j++)
        __builtin_amdgcn_global_load_lds(AS1(A + (size_t)(bm + rSA[j]) * K + cSA[j] * 8),
                                         AS3(&Asl[0][(w * 2 + j) * 512]), 16, 0, 0);
    #pragma unroll
    for (int j = 0; j < 4; j++)
        __builtin_amdgcn_global_load_lds(AS1(W + (size_t)rSB[j] * K + cSB[j] * 8),
                                         AS3(&Bsl[0][(w * 4 + j) * 512]), 16, 0, 0);

    for (int kk = 0; kk < nK; kk++) {
        const int cur = kk & 1;
        __syncthreads();
        if (kk + 1 < nK) {
            const int k1 = (kk + 1) * 64;
            #pragma unroll
            for (int j = 0; j < 2; j++)
                __builtin_amdgcn_global_load_lds(AS1(A + (size_t)(bm + rSA[j]) * K + k1 + cSA[j] * 8),
                                                 AS3(&Asl[cur ^ 1][(w * 2 + j) * 512]), 16, 0, 0);
            #pragma unroll
            for (int j = 0; j < 4; j++)
                __builtin_amdgcn_global_load_lds(AS1(W + (size_t)rSB[j] * K + k1 + cSB[j] * 8),
                                                 AS3(&Bsl[cur ^ 1][(w * 4 + j) * 512]), 16, 0, 0);
        }
        #pragma unroll
        for (int ks = 0; ks < 2; ks++) {
            frag16 af[4], bf[2];
            #pragma unroll
            for (int mt = 0; mt < 4; mt++) {
                int r = mt * 16 + l16;
                af[mt] = *(const frag16*)&Asl[cur][r * 64 + (((ks * 4 + quad) ^ (r & 7)) * 8)];
            }
            #pragma unroll
            for (int nt = 0; nt < 2; nt++) {
                int r = w * 32 + nt * 16 + l16;
                bf[nt] = *(const frag16*)&Bsl[cur][r * 64 + (((ks * 4 + quad) ^ (r & 7)) * 8)];
            }
            #pragma unroll
            for (int mt = 0; mt < 4; mt++)
                #pragma unroll
                for (int nt = 0; nt < 2; nt++)
                    acc[mt][nt] = __builtin_amdgcn_mfma_f32_16x16x32_bf16(af[mt], bf[nt], acc[mt][nt], 0, 0, 0);
        }
    }
    #pragma unroll
    for (int mt = 0; mt < 4; mt++) {
        #pragma unroll
        for (int reg = 0; reg < 4; reg++) {
            int row = bm + mt * 16 + quad * 4 + reg;
            #pragma unroll
            for (int nt = 0; nt < 2; nt++) {
                int col = bn + w * 32 + nt * 16 + l16;
                if (col < N) {
                    if constexpr (BF16OUT)
                        ((__hip_bfloat16*)Cv)[(size_t)row * N + col] = __float2bfloat16(acc[mt][nt][reg]);
                    else
                        ((float*)Cv)[(size_t)row * N + col] = acc[mt][nt][reg];
                }
            }
        }
    }
}

// ---------------- RoPE + rank contraction, 4 tokens/block ----------
// Reads bf16 abqkv (packed 2xbf16 = 4B/lane loads), stages fp32 in LDS.
__global__ __launch_bounds__(256) void qkv_kernel(
    const __hip_bfloat16* __restrict__ ab,
    __hip_bfloat16* __restrict__ q, __hip_bfloat16* __restrict__ k,
    __hip_bfloat16* __restrict__ vT)
{
    const int tok0 = blockIdx.x * 4;
    const int w = threadIdx.x >> 6;
    const int d = threadIdx.x & 63;
    const int token = tok0 + w;
    const int b = token / TT;
    const int t = token % TT;
    __shared__ float sab[4][NQK];
    __shared__ __align__(8) __hip_bfloat16 vbuf[NHEADS][DHEAD][4];
    const __hip_bfloat16* aq = ab + (size_t)token * NQK;
    #pragma unroll
    for (int i2 = d; i2 < NQK / 2; i2 += 64) {
        unsigned int u = *(const unsigned int*)&aq[i2 * 2];
        sab[w][i2 * 2 + 0] = bfu2f((unsigned short)(u & 0xffff));
        sab[w][i2 * 2 + 1] = bfu2f((unsigned short)(u >> 16));
    }
    const float* sq  = sab[w];
    const float* skv = sab[w] + 480;
    const int i32 = d & 31;
    // 10000^(-i/32) = 2^(-i/32 * log2(10000))
    float inv_freq = exp2_hw(-(float)i32 * (13.287712379549449f / 32.0f));
    float fr = (float)t * inv_freq;
    float c = cosf(fr), s = sinf(fr);
    __syncthreads();
    float rot[4];
    #pragma unroll
    for (int r = 0; r < 4; r++) {
        float x1 = skv[r * CHDIM + NHEADS + i32];
        float x2 = skv[r * CHDIM + NHEADS + 32 + i32];
        rot[r] = (d < 32) ? (x1 * c + x2 * s) : (-x1 * s + x2 * c);
    }
    float bqv[RQn];
    #pragma unroll
    for (int r = 0; r < RQn; r++) bqv[r] = sq[r * CHDIM + NHEADS + d];
    #pragma unroll
    for (int h = 0; h < NHEADS; h++) {
        float accq = 0.0f;
        #pragma unroll
        for (int r = 0; r < RQn; r++)
            accq += sq[r * CHDIM + h] * bqv[r];
        // q-scale: 1/sqrt(64)/RQ with log2(e) folded in (flash uses 2^x).
        q[((size_t)(b * NHEADS + h) * TT + t) * DHEAD + d] =
            __float2bfloat16(accq * (0.125f / 6.0f) * 1.4426950408889634f);
        float acck = 0.0f, accv = 0.0f;
        #pragma unroll
        for (int r = 0; r < RKn; r++)
            acck += skv[r * CHDIM + h] * rot[r];
        #pragma unroll
        for (int r = 0; r < RVn; r++)
            accv += skv[(RKn + r) * CHDIM + h] * rot[RKn + r];
        k[((size_t)(b * NHEADS + h) * TT + t) * DHEAD + d] = __float2bfloat16(acck * 0.5f);
        vbuf[h][d][w] = __float2bfloat16(accv * 0.5f);
    }
    __syncthreads();
    const int t0 = tok0 % TT;
    const int b0 = tok0 / TT;
    for (int row = threadIdx.x; row < NHEADS * DHEAD; row += 256) {
        int h = row >> 6, dd = row & 63;
        *(uint2*)&vT[((size_t)(b0 * NHEADS + h) * DHEAD + dd) * TT + t0] =
            *(const uint2*)&vbuf[h][dd][0];
    }
}

// -------- P^T B-frag construction from exp'd S registers (shared helper) ----
// __builtin_amdgcn_permlane32_swap(A,B,fi,bc) -> {A',B'} where
//   A' = {A.lo lanes 0-31, B.lo delivered to lanes 32-63}
//   B' = {A.hi delivered to lanes 0-31, B.hi lanes 32-63}
static __device__ __forceinline__ void build_pfrag(
    const float* s0, const float* s1, frag16 Pf[4])
{
    #pragma unroll
    for (int k2 = 0; k2 < 4; k2++) {
        const float* sF = (k2 >= 2) ? s1 : s0;
        const int bs = 8 * (k2 & 1);
        unsigned int a0 = pk2(sF[bs + 0], sF[bs + 1]);
        unsigned int b0 = pk2(sF[bs + 2], sF[bs + 3]);
        unsigned int a1 = pk2(sF[bs + 4], sF[bs + 5]);
        unsigned int b1 = pk2(sF[bs + 6], sF[bs + 7]);
        uint2v ra = __builtin_amdgcn_permlane32_swap(a0, a1, false, false);
        uint2v rb = __builtin_amdgcn_permlane32_swap(b0, b1, false, false);
        union { frag16 f; unsigned int u[4]; } pf;
        pf.u[0] = ra[0]; pf.u[1] = rb[0]; pf.u[2] = ra[1]; pf.u[3] = rb[1];
        Pf[k2] = pf.f;
    }
}

// ---------- single attention tile, operands direct from global (L2) --------
// K/V per XCD working set = 2MB (XCD pinning) -> L2-resident; no LDS staging,
// no barriers, no vmcnt(0) drains. Load order: 8 K-frags, 8 V-frags (16
// independent loads in flight), QK chain waits K only; exp/pack hides V.
static __device__ __forceinline__ void attn_tile_direct(
    const __hip_bfloat16* __restrict__ Kt,   // K[phys*64 ..][d]   row-stride 64
    const __hip_bfloat16* __restrict__ Vt,   // V^T[d][phys*64 ..] row-stride TT
    const frag16 qB[4], f32x16& O0, f32x16& O1, float& lpart,
    const int l31, const int hi,
    const bool domask, const int kb0, const int qlane)
{
    frag16 kf0[4], kf1[4];
    #pragma unroll
    for (int kt4 = 0; kt4 < 4; kt4++) {
        const int c8 = kt4 * 2 + hi;
        kf0[kt4] = *(const frag16*)&Kt[(size_t)l31 * 64 + c8 * 8];
        kf1[kt4] = *(const frag16*)&Kt[(size_t)(32 + l31) * 64 + c8 * 8];
    }
    frag16 vf0[4], vf1[4];
    #pragma unroll
    for (int k2 = 0; k2 < 4; k2++) {
        const int c8 = k2 * 2 + hi;
        vf0[k2] = *(const frag16*)&Vt[(size_t)l31 * TT + c8 * 8];
        vf1[k2] = *(const frag16*)&Vt[(size_t)(32 + l31) * TT + c8 * 8];
    }
    f32x16 ST0 = {}, ST1 = {};
    __builtin_amdgcn_s_setprio(1);
    #pragma unroll
    for (int kt4 = 0; kt4 < 4; kt4++) {
        ST0 = __builtin_amdgcn_mfma_f32_32x32x16_bf16(kf0[kt4], qB[kt4], ST0, 0, 0, 0);
        ST1 = __builtin_amdgcn_mfma_f32_32x32x16_bf16(kf1[kt4], qB[kt4], ST1, 0, 0, 0);
    }
    __builtin_amdgcn_s_setprio(0);
    float* s0 = (float*)&ST0;
    float* s1 = (float*)&ST1;
    if (domask) {
        int kbq = kb0 + 4 * hi;
        #pragma unroll
        for (int reg = 0; reg < 16; reg++) {
            int rowc = (reg & 3) + 8 * (reg >> 2);
            if (kbq + rowc > qlane)      s0[reg] = -1e30f;
            if (kbq + 32 + rowc > qlane) s1[reg] = -1e30f;
        }
    }
    #pragma unroll
    for (int reg = 0; reg < 16; reg++) {
        float p0 = exp2_hw(s0[reg]);
        float p1 = exp2_hw(s1[reg]);
        s0[reg] = p0; s1[reg] = p1;
        lpart += p0 + p1;
    }
    frag16 Pf[4];
    build_pfrag(s0, s1, Pf);
    __builtin_amdgcn_s_setprio(1);
    #pragma unroll
    for (int k2 = 0; k2 < 4; k2++) {
        O0 = __builtin_amdgcn_mfma_f32_32x32x16_bf16(vf0[k2], Pf[k2], O0, 0, 0, 0);
        O1 = __builtin_amdgcn_mfma_f32_32x32x16_bf16(vf1[k2], Pf[k2], O1, 0, 0, 0);
    }
    __builtin_amdgcn_s_setprio(0);
}

// ------------- split-K causal flash attention, 4096 1-wave blocks -----------
// Block = one wave: (bh, qt, part, w). Wave owns 32 q-rows (qlane range) and
// its K-half; fully independent -> no __syncthreads anywhere, TLP elastic.
// Bid layout: [2:0]=xcd (T1 pinning: 4 bh/XCD => 2MB K/V in 4MB L2),
// [4:3]=bh-sub, [7:5]=i8 (qtoff,part), [9:8]=qt group, [11:10]=w.
__global__ __launch_bounds__(64) void flash_mfma(
    const __hip_bfloat16* __restrict__ q, const __hip_bfloat16* __restrict__ k,
    const __hip_bfloat16* __restrict__ vT,
    float* __restrict__ Op, float* __restrict__ Lp)
{
    const int Bid = blockIdx.x;          // 4096
    const int m  = Bid & 255;
    const int g  = (Bid >> 8) & 3;
    const int w  = Bid >> 10;            // 0..3
    const int xcd = m & 7;
    const int bh  = xcd * 4 + ((m >> 3) & 3);
    const int i8  = m >> 5;              // 0..7
    const int qtoff = i8 >> 1;
    const int part  = i8 & 1;
    const int qt = (g == 0) ? (15 - qtoff) : (g == 1) ? qtoff
                 : (g == 2) ? (11 - qtoff) : (4 + qtoff);
    const int nst = qt + 1;
    const int k0  = part * nst;

    const int lane = threadIdx.x;
    const int l31 = lane & 31;
    const int hi = lane >> 5;
    const int paddr = (lane ^ 32) << 2;

    const size_t base = (size_t)bh * TT * DHEAD;
    const __hip_bfloat16* qb = q + base;
    const __hip_bfloat16* kb = k + base;
    const __hip_bfloat16* vb = vT + base;

    const int ktd = 2 * qt + (w >> 1);           // this wave's diagonal tile
    const int qlane = qt * 128 + w * 32 + l31;   // this lane's q row
    const int kend = k0 + nst;
    const int pend = (kend < ktd + 1) ? kend : (ktd + 1);

    frag16 qB[4];
    #pragma unroll
    for (int kt4 = 0; kt4 < 4; kt4++)
        qB[kt4] = *(const frag16*)&qb[(size_t)qlane * DHEAD + kt4 * 16 + hi * 8];

    f32x16 O0 = {}, O1 = {};
    float l = 0.0f;

    for (int phys = k0; phys < pend; phys++) {
        attn_tile_direct(kb + (size_t)phys * 64 * DHEAD, vb + (size_t)phys * 64,
                         qB, O0, O1, l, l31, hi,
                         phys == ktd, phys * 64, qlane);
    }

    // epilogue: partial O (fp32) + partial l, combined downstream
    float lother = __int_as_float(__builtin_amdgcn_ds_bpermute(paddr, __float_as_int(l)));
    float ltot = l + lother;
    const int slot = bh * 16 + qt;               // 0..511
    const int rloc = w * 32 + l31;               // 0..127
    float* Od = Op + ((size_t)part * 512 + slot) * 8192 + (size_t)rloc * 64;
    float* o0 = (float*)&O0;
    float* o1 = (float*)&O1;
    #pragma unroll
    for (int gg = 0; gg < 4; gg++) {
        int d0 = 8 * gg + 4 * hi;
        *(float4*)&Od[d0]      = (float4){o0[4*gg+0], o0[4*gg+1], o0[4*gg+2], o0[4*gg+3]};
        *(float4*)&Od[32 + d0] = (float4){o1[4*gg+0], o1[4*gg+1], o1[4*gg+2], o1[4*gg+3]};
    }
    if (hi == 0) Lp[part * 65536 + slot * 128 + rloc] = ltot;
}

// ---------------- combine the two K-half partials, normalize, write y -------
// 2048 blocks, 8 cols/thread: 2x32B reads per partial + 16B bf16 store.
__global__ __launch_bounds__(256) void combine(
    const float* __restrict__ Op, const float* __restrict__ Lp,
    __hip_bfloat16* __restrict__ y)
{
    int idx = blockIdx.x * 256 + threadIdx.x;   // 0..524287
    int cg = (idx & 7) * 8;                     // col group start
    int rowslot = idx >> 3;                     // 0..65535
    int slot = rowslot >> 7, row = rowslot & 127;
    int bh = slot >> 4, qt = slot & 15;
    int b = bh >> 4, h = bh & 15;
    int qrow = qt * 128 + row;
    float l0 = Lp[slot * 128 + row];
    float l1 = Lp[65536 + slot * 128 + row];
    float inv = 1.0f / (l0 + l1);
    const float* p0 = Op + (size_t)rowslot * 64 + cg;
    const float* p1 = p0 + 4194304;
    __hip_bfloat16* yp = y + ((size_t)(b * TT + qrow)) * DDim + h * DHEAD + cg;
    float4 a0 = *(const float4*)&p0[0];
    float4 a1 = *(const float4*)&p0[4];
    float4 b0 = *(const float4*)&p1[0];
    float4 b1 = *(const float4*)&p1[4];
    uint4 o;
    o.x = pk2((a0.x + b0.x) * inv, (a0.y + b0.y) * inv);
    o.y = pk2((a0.z + b0.z) * inv, (a0.w + b0.w) * inv);
    o.z = pk2((a1.x + b1.x) * inv, (a1.y + b1.y) * inv);
    o.w = pk2((a1.z + b1.z) * inv, (a1.w + b1.w) * inv);
    *(uint4*)&yp[0] = o;
}

extern "C" void kernel_launch(void* const* d_in, const int* in_sizes, int n_in,
                              void* d_out, int out_size, void* d_ws, size_t ws_size,
                              hipStream_t stream) {
    const float* x      = (const float*)d_in[0];
    const float* W_abq  = (const float*)d_in[1];
    const float* W_abkv = (const float*)d_in[2];
    const float* W_o    = (const float*)d_in[3];
    float* out = (float*)d_out;

    char* ws = (char*)d_ws;
    __hip_bfloat16* xb   = (__hip_bfloat16*)ws;  ws += (size_t)4194304 * 2;
    __hip_bfloat16* wqk  = (__hip_bfloat16*)ws;  ws += (size_t)NQK * 1024 * 2;
    __hip_bfloat16* wo_b = (__hip_bfloat16*)ws;  ws += (size_t)1048576 * 2;
    __hip_bfloat16* abqkv = (__hip_bfloat16*)ws; ws += (size_t)4096 * NQK * 2;
    __hip_bfloat16* qb = (__hip_bfloat16*)ws;    ws += (size_t)4194304 * 2;
    __hip_bfloat16* kb = (__hip_bfloat16*)ws;    ws += (size_t)4194304 * 2;
    __hip_bfloat16* vT = (__hip_bfloat16*)ws;    ws += (size_t)4194304 * 2;
    __hip_bfloat16* yb = (__hip_bfloat16*)ws;    ws += (size_t)4194304 * 2;
    float* Op = (float*)ws;                      ws += (size_t)2 * 4194304 * 4;
    float* Lp = (float*)ws;                      ws += (size_t)2 * 65536 * 4;

    cvt_all<<<dim3(5920), dim3(256), 0, stream>>>(x, W_abq, W_abkv, W_o, xb, wqk, wo_b);
    gemm_bf16<true><<<dim3(7, 64), dim3(256), 0, stream>>>(xb, wqk, abqkv, 4096, NQK, 1024);
    qkv_kernel<<<dim3(1024), dim3(256), 0, stream>>>(abqkv, qb, kb, vT);
    flash_mfma<<<dim3(4096), dim3(64), 0, stream>>>(qb, kb, vT, Op, Lp);
    combine<<<dim3(2048), dim3(256), 0, stream>>>(Op, Lp, yb);
    gemm_bf16<false><<<dim3(8, 64), dim3(256), 0, stream>>>(yb, wo_b, out, 4096, 1024, 1024);
}

// Round 9
// 157.847 us; speedup vs baseline: 1.3317x; 1.3317x over previous
//
#include <hip/hip_runtime.h>
#include <hip/hip_bf16.h>
#include <math.h>

#define NHEADS 16
#define DHEAD  64
#define CHDIM  80
#define RQn    6
#define RKn    2
#define RVn    2
#define BB     2
#define TT     2048
#define DDim   1024
#define NQK    800   // 480 + 320 combined projection rows

using frag16 = __attribute__((ext_vector_type(8))) short;   // 8 bf16 (4 VGPR)
using f32x4  = __attribute__((ext_vector_type(4))) float;   // 4 fp32 acc
using f32x16 = __attribute__((ext_vector_type(16))) float;  // 32x32 acc
using uint2v = __attribute__((ext_vector_type(2))) unsigned int;

#define AS1(p) ((const __attribute__((address_space(1))) unsigned int*)(p))
#define AS3(p) ((__attribute__((address_space(3))) unsigned int*)(p))

static __device__ __forceinline__ unsigned short bf16_bits(float f) {
    __hip_bfloat16 h = __float2bfloat16(f);
    return *(unsigned short*)&h;
}
static __device__ __forceinline__ unsigned int pk2(float a, float b) {
    return ((unsigned int)bf16_bits(b) << 16) | (unsigned int)bf16_bits(a);
}
static __device__ __forceinline__ float bfu2f(unsigned short u) {
    return __uint_as_float(((unsigned int)u) << 16);
}
// HW exp2 via the proper intrinsic (hazard-safe). log2(e) folded into q-scale.
static __device__ __forceinline__ float exp2_hw(float x) {
    return __builtin_amdgcn_exp2f(x);
}

// ---------------- fused fp32 -> bf16 convert (4 segments, 1 launch) ----------
__global__ __launch_bounds__(256) void cvt_all(
    const float* __restrict__ x, const float* __restrict__ wq,
    const float* __restrict__ wk, const float* __restrict__ wo,
    __hip_bfloat16* __restrict__ xb, __hip_bfloat16* __restrict__ wqk,
    __hip_bfloat16* __restrict__ wob)
{
    int bid = blockIdx.x;
    const float* src; __hip_bfloat16* dst; int n4;
    if (bid < 4096)      { src = x;  dst = xb;            n4 = 1048576; }
    else if (bid < 4576) { bid -= 4096; src = wq; dst = wqk;           n4 = 122880; }
    else if (bid < 4896) { bid -= 4576; src = wk; dst = wqk + 491520;  n4 = 81920; }
    else                 { bid -= 4896; src = wo; dst = wob;           n4 = 262144; }
    int i = bid * 256 + threadIdx.x;
    if (i < n4) {
        float4 v = *(const float4*)&src[i * 4];
        ushort4 o;
        o.x = bf16_bits(v.x); o.y = bf16_bits(v.y);
        o.z = bf16_bits(v.z); o.w = bf16_bits(v.w);
        *(ushort4*)&dst[i * 4] = o;
    }
}

// ---------- GEMM: C[M,N] = A[M,K]_bf16 * W[N,K]_bf16^T, 64x128 tile ---------
// BF16OUT: write bf16 C (used for abqkv to halve the round-trip traffic).
template <bool BF16OUT>
__global__ __launch_bounds__(256) void gemm_bf16(
    const __hip_bfloat16* __restrict__ A, const __hip_bfloat16* __restrict__ W,
    void* __restrict__ Cv, int M, int N, int K)
{
    __shared__ __hip_bfloat16 Asl[2][64 * 64];
    __shared__ __hip_bfloat16 Bsl[2][128 * 64];
    const int tid = threadIdx.x;
    const int w = tid >> 6, lane = tid & 63;
    const int l16 = lane & 15, quad = lane >> 4;
    const int bm = blockIdx.y * 64, bn = blockIdx.x * 128;

    // staging geometry
    int rSA[2], cSA[2];
    #pragma unroll
    for (int j = 0; j < 2; j++) {
        int L = (w * 2 + j) * 64 + lane;
        rSA[j] = L >> 3;
        cSA[j] = (L & 7) ^ (rSA[j] & 7);
    }
    int rSB[4], cSB[4];
    #pragma unroll
    for (int j = 0; j < 4; j++) {
        int L = (w * 4 + j) * 64 + lane;
        int r = L >> 3;
        cSB[j] = (L & 7) ^ (r & 7);
        int rb = bn + r;
        rSB[j] = (rb < N) ? rb : (N - 1);
    }

    f32x4 acc[4][2];
    #pragma unroll
    for (int mt = 0; mt < 4; mt++)
        #pragma unroll
        for (int nt = 0; nt < 2; nt++)
            acc[mt][nt] = (f32x4){0.f, 0.f, 0.f, 0.f};

    const int nK = K >> 6;
    #pragma unroll
    for (int j = 0; j < 2; j++)
        __builtin_amdgcn_global_load_lds(AS1(A + (size_t)(bm + rSA[j]) * K + cSA[j] * 8),
                                         AS3(&Asl[0][(w * 2 + j) * 512]), 16, 0, 0);
    #pragma unroll
    for (int j = 0; j < 4; j++)
        __builtin_amdgcn_global_load_lds(AS1(W + (size_t)rSB[j] * K + cSB[j] * 8),
                                         AS3(&Bsl[0][(w * 4 + j) * 512]), 16, 0, 0);

    for (int kk = 0; kk < nK; kk++) {
        const int cur = kk & 1;
        __syncthreads();
        if (kk + 1 < nK) {
            const int k1 = (kk + 1) * 64;
            #pragma unroll
            for (int j = 0; j < 2; j++)
                __builtin_amdgcn_global_load_lds(AS1(A + (size_t)(bm + rSA[j]) * K + k1 + cSA[j] * 8),
                                                 AS3(&Asl[cur ^ 1][(w * 2 + j) * 512]), 16, 0, 0);
            #pragma unroll
            for (int j = 0; j < 4; j++)
                __builtin_amdgcn_global_load_lds(AS1(W + (size_t)rSB[j] * K + k1 + cSB[j] * 8),
                                                 AS3(&Bsl[cur ^ 1][(w * 4 + j) * 512]), 16, 0, 0);
        }
        #pragma unroll
        for (int ks = 0; ks < 2; ks++) {
            frag16 af[4], bf[2];
            #pragma unroll
            for (int mt = 0; mt < 4; mt++) {
                int r = mt * 16 + l16;
                af[mt] = *(const frag16*)&Asl[cur][r * 64 + (((ks * 4 + quad) ^ (r & 7)) * 8)];
            }
            #pragma unroll
            for (int nt = 0; nt < 2; nt++) {
                int r = w * 32 + nt * 16 + l16;
                bf[nt] = *(const frag16*)&Bsl[cur][r * 64 + (((ks * 4 + quad) ^ (r & 7)) * 8)];
            }
            #pragma unroll
            for (int mt = 0; mt < 4; mt++)
                #pragma unroll
                for (int nt = 0; nt < 2; nt++)
                    acc[mt][nt] = __builtin_amdgcn_mfma_f32_16x16x32_bf16(af[mt], bf[nt], acc[mt][nt], 0, 0, 0);
        }
    }
    #pragma unroll
    for (int mt = 0; mt < 4; mt++) {
        #pragma unroll
        for (int reg = 0; reg < 4; reg++) {
            int row = bm + mt * 16 + quad * 4 + reg;
            #pragma unroll
            for (int nt = 0; nt < 2; nt++) {
                int col = bn + w * 32 + nt * 16 + l16;
                if (col < N) {
                    if constexpr (BF16OUT)
                        ((__hip_bfloat16*)Cv)[(size_t)row * N + col] = __float2bfloat16(acc[mt][nt][reg]);
                    else
                        ((float*)Cv)[(size_t)row * N + col] = acc[mt][nt][reg];
                }
            }
        }
    }
}

// ---------------- RoPE + rank contraction, 4 tokens/block ----------
// Reads bf16 abqkv (packed 2xbf16 = 4B/lane loads), stages fp32 in LDS.
__global__ __launch_bounds__(256) void qkv_kernel(
    const __hip_bfloat16* __restrict__ ab,
    __hip_bfloat16* __restrict__ q, __hip_bfloat16* __restrict__ k,
    __hip_bfloat16* __restrict__ vT)
{
    const int tok0 = blockIdx.x * 4;
    const int w = threadIdx.x >> 6;
    const int d = threadIdx.x & 63;
    const int token = tok0 + w;
    const int b = token / TT;
    const int t = token % TT;
    __shared__ float sab[4][NQK];
    __shared__ __align__(8) __hip_bfloat16 vbuf[NHEADS][DHEAD][4];
    const __hip_bfloat16* aq = ab + (size_t)token * NQK;
    #pragma unroll
    for (int i2 = d; i2 < NQK / 2; i2 += 64) {
        unsigned int u = *(const unsigned int*)&aq[i2 * 2];
        sab[w][i2 * 2 + 0] = bfu2f((unsigned short)(u & 0xffff));
        sab[w][i2 * 2 + 1] = bfu2f((unsigned short)(u >> 16));
    }
    const float* sq  = sab[w];
    const float* skv = sab[w] + 480;
    const int i32 = d & 31;
    // 10000^(-i/32) = 2^(-i/32 * log2(10000))
    float inv_freq = exp2_hw(-(float)i32 * (13.287712379549449f / 32.0f));
    float fr = (float)t * inv_freq;
    float c = cosf(fr), s = sinf(fr);
    __syncthreads();
    float rot[4];
    #pragma unroll
    for (int r = 0; r < 4; r++) {
        float x1 = skv[r * CHDIM + NHEADS + i32];
        float x2 = skv[r * CHDIM + NHEADS + 32 + i32];
        rot[r] = (d < 32) ? (x1 * c + x2 * s) : (-x1 * s + x2 * c);
    }
    float bqv[RQn];
    #pragma unroll
    for (int r = 0; r < RQn; r++) bqv[r] = sq[r * CHDIM + NHEADS + d];
    #pragma unroll
    for (int h = 0; h < NHEADS; h++) {
        float accq = 0.0f;
        #pragma unroll
        for (int r = 0; r < RQn; r++)
            accq += sq[r * CHDIM + h] * bqv[r];
        // q-scale: 1/sqrt(64)/RQ with log2(e) folded in (flash uses 2^x).
        q[((size_t)(b * NHEADS + h) * TT + t) * DHEAD + d] =
            __float2bfloat16(accq * (0.125f / 6.0f) * 1.4426950408889634f);
        float acck = 0.0f, accv = 0.0f;
        #pragma unroll
        for (int r = 0; r < RKn; r++)
            acck += skv[r * CHDIM + h] * rot[r];
        #pragma unroll
        for (int r = 0; r < RVn; r++)
            accv += skv[(RKn + r) * CHDIM + h] * rot[RKn + r];
        k[((size_t)(b * NHEADS + h) * TT + t) * DHEAD + d] = __float2bfloat16(acck * 0.5f);
        vbuf[h][d][w] = __float2bfloat16(accv * 0.5f);
    }
    __syncthreads();
    const int t0 = tok0 % TT;
    const int b0 = tok0 / TT;
    for (int row = threadIdx.x; row < NHEADS * DHEAD; row += 256) {
        int h = row >> 6, dd = row & 63;
        *(uint2*)&vT[((size_t)(b0 * NHEADS + h) * DHEAD + dd) * TT + t0] =
            *(const uint2*)&vbuf[h][dd][0];
    }
}

// -------- P^T B-frag construction from exp'd S registers (shared helper) ----
// __builtin_amdgcn_permlane32_swap(A,B,fi,bc) -> {A',B'} where
//   A' = {A.lo lanes 0-31, B.lo delivered to lanes 32-63}
//   B' = {A.hi delivered to lanes 0-31, B.hi lanes 32-63}
static __device__ __forceinline__ void build_pfrag(
    const float* s0, const float* s1, frag16 Pf[4])
{
    #pragma unroll
    for (int k2 = 0; k2 < 4; k2++) {
        const float* sF = (k2 >= 2) ? s1 : s0;
        const int bs = 8 * (k2 & 1);
        unsigned int a0 = pk2(sF[bs + 0], sF[bs + 1]);
        unsigned int b0 = pk2(sF[bs + 2], sF[bs + 3]);
        unsigned int a1 = pk2(sF[bs + 4], sF[bs + 5]);
        unsigned int b1 = pk2(sF[bs + 6], sF[bs + 7]);
        uint2v ra = __builtin_amdgcn_permlane32_swap(a0, a1, false, false);
        uint2v rb = __builtin_amdgcn_permlane32_swap(b0, b1, false, false);
        union { frag16 f; unsigned int u[4]; } pf;
        pf.u[0] = ra[0]; pf.u[1] = rb[0]; pf.u[2] = ra[1]; pf.u[3] = rb[1];
        Pf[k2] = pf.f;
    }
}

// ---------------- single attention tile (LDS operands, XOR-swizzled) --------
static __device__ __forceinline__ void attn_tile(
    const __hip_bfloat16* __restrict__ Kc, const __hip_bfloat16* __restrict__ Vc,
    const frag16 qB[4], f32x16& O0, f32x16& O1, float& lpart,
    const int l31, const int hi, const int xi,
    const bool domask, const int kb0, const int qlane)
{
    f32x16 ST0 = {}, ST1 = {};
    __builtin_amdgcn_s_setprio(1);
    #pragma unroll
    for (int kt4 = 0; kt4 < 4; kt4++) {
        int c8 = kt4 * 2 + hi;
        frag16 kf0 = *(const frag16*)&Kc[l31 * 64 + ((c8 ^ xi) * 8)];
        frag16 kf1 = *(const frag16*)&Kc[(32 + l31) * 64 + ((c8 ^ xi) * 8)];
        ST0 = __builtin_amdgcn_mfma_f32_32x32x16_bf16(kf0, qB[kt4], ST0, 0, 0, 0);
        ST1 = __builtin_amdgcn_mfma_f32_32x32x16_bf16(kf1, qB[kt4], ST1, 0, 0, 0);
    }
    __builtin_amdgcn_s_setprio(0);
    float* s0 = (float*)&ST0;
    float* s1 = (float*)&ST1;
    if (domask) {
        int kbq = kb0 + 4 * hi;
        #pragma unroll
        for (int reg = 0; reg < 16; reg++) {
            int rowc = (reg & 3) + 8 * (reg >> 2);
            if (kbq + rowc > qlane)      s0[reg] = -1e30f;
            if (kbq + 32 + rowc > qlane) s1[reg] = -1e30f;
        }
    }
    #pragma unroll
    for (int reg = 0; reg < 16; reg++) {
        float p0 = exp2_hw(s0[reg]);
        float p1 = exp2_hw(s1[reg]);
        s0[reg] = p0; s1[reg] = p1;
        lpart += p0 + p1;
    }
    frag16 Pf[4];
    build_pfrag(s0, s1, Pf);
    __builtin_amdgcn_s_setprio(1);
    #pragma unroll
    for (int k2 = 0; k2 < 4; k2++) {
        int c8 = k2 * 2 + hi;
        frag16 vf0 = *(const frag16*)&Vc[l31 * 64 + ((c8 ^ xi) * 8)];
        frag16 vf1 = *(const frag16*)&Vc[(32 + l31) * 64 + ((c8 ^ xi) * 8)];
        O0 = __builtin_amdgcn_mfma_f32_32x32x16_bf16(vf0, Pf[k2], O0, 0, 0, 0);
        O1 = __builtin_amdgcn_mfma_f32_32x32x16_bf16(vf1, Pf[k2], O1, 0, 0, 0);
    }
    __builtin_amdgcn_s_setprio(0);
}

// ------- fused split-K causal flash attention, 512-thread blocks ------------
// Block = (bh, qt): 8 waves. Waves 0-3 = K-half 0 [0,qt+1), waves 4-7 =
// K-half 1 [qt+1, 2qt+2). Each half has its own dbuf K/V staging region
// (64KB LDS total -> 2 blocks/CU = 16 waves/CU). Both halves run identical
// nst=qt+1 step counts -> per-step barriers align. Epilogue: part-1 waves
// drop O/l into LDS (over dead staging, pad-33 swizzle = conflict-free);
// part-0 adds, normalizes with full row-sum, writes y bf16 directly.
// No Op/Lp partials, no combine kernel (-105MB HBM traffic vs R6).
// Balance: Bid c / c+256 carry complementary qt (15-x / x), descending first.
// XCD pinning (T1): Bid&7 = XCD, 4 bh/XCD -> 2MB K/V set in 4MB L2.
__global__ __launch_bounds__(512, 4) void flash_mfma(
    const __hip_bfloat16* __restrict__ q, const __hip_bfloat16* __restrict__ k,
    const __hip_bfloat16* __restrict__ vT, __hip_bfloat16* __restrict__ y)
{
    const int Bid = blockIdx.x;          // 512
    const int m = Bid & 255;
    const int half = Bid >> 8;
    const int xcd = m & 7;
    const int bh  = xcd * 4 + ((m >> 3) & 3);
    const int qx  = m >> 5;              // 0..7
    const int qt  = half ? qx : (15 - qx);
    const int nst = qt + 1;

    const int tid = threadIdx.x;
    const int w8 = tid >> 6;             // 0..7
    const int part = w8 >> 2;
    const int w = w8 & 3;
    const int lane = tid & 63;
    const int l31 = lane & 31;
    const int hi = lane >> 5;
    const int xi = l31 & 7;
    const int paddr = (lane ^ 32) << 2;
    const int k0 = part * nst;

    __shared__ __align__(16) char smem[65536];
    __hip_bfloat16* Ks = (__hip_bfloat16*)(smem + part * 32768);           // [2][4096]
    __hip_bfloat16* Vs = (__hip_bfloat16*)(smem + part * 32768 + 16384);   // [2][4096]

    const size_t base = (size_t)bh * TT * DHEAD;
    const __hip_bfloat16* qb = q + base;
    const __hip_bfloat16* kb = k + base;
    const __hip_bfloat16* vb = vT + base;

    const int ktd = 2 * qt + (w >> 1);           // this wave's diagonal tile
    const int qlane = qt * 128 + w * 32 + l31;   // this lane's q row

    int offK[2], offV[2];
    #pragma unroll
    for (int j = 0; j < 2; j++) {
        int Lc = w * 128 + j * 64 + lane;
        int r = Lc >> 3, c8 = Lc & 7, g8 = c8 ^ (r & 7);
        offK[j] = r * 64 + g8 * 8;
        offV[j] = r * TT + g8 * 8;
    }

    frag16 qB[4];
    #pragma unroll
    for (int kt4 = 0; kt4 < 4; kt4++)
        qB[kt4] = *(const frag16*)&qb[(size_t)qlane * DHEAD + kt4 * 16 + hi * 8];

    f32x16 O0 = {}, O1 = {};
    float l = 0.0f;

    #pragma unroll
    for (int j = 0; j < 2; j++) {
        __builtin_amdgcn_global_load_lds(AS1(kb + (size_t)k0 * 4096 + offK[j]),
                                         AS3(&Ks[w * 1024 + j * 512]), 16, 0, 0);
        __builtin_amdgcn_global_load_lds(AS1(vb + (size_t)k0 * 64 + offV[j]),
                                         AS3(&Vs[w * 1024 + j * 512]), 16, 0, 0);
    }

    for (int kt = 0; kt < nst; kt++) {
        const int cur = kt & 1;
        __syncthreads();
        if (kt + 1 < nst) {
            const int phys1 = k0 + kt + 1;
            #pragma unroll
            for (int j = 0; j < 2; j++) {
                __builtin_amdgcn_global_load_lds(AS1(kb + (size_t)phys1 * 4096 + offK[j]),
                                                 AS3(&Ks[(cur ^ 1) * 4096 + w * 1024 + j * 512]), 16, 0, 0);
                __builtin_amdgcn_global_load_lds(AS1(vb + (size_t)phys1 * 64 + offV[j]),
                                                 AS3(&Vs[(cur ^ 1) * 4096 + w * 1024 + j * 512]), 16, 0, 0);
            }
        }
        const int phys = k0 + kt;
        if (phys <= ktd)
            attn_tile(Ks + cur * 4096, Vs + cur * 4096, qB, O0, O1, l,
                      l31, hi, xi, phys == ktd, phys * 64, qlane);
    }

    // ---- in-block combine: part1 -> LDS (over dead staging), part0 adds ----
    __syncthreads();                       // all staging reads complete
    float* Oex = (float*)smem;             // 4 pairs x 64 lanes x 33 floats
    float* lex = (float*)(smem + 33792);   // 4 x 64 floats
    float* o0 = (float*)&O0;
    float* o1 = (float*)&O1;
    if (part == 1) {
        float* dst = Oex + (w * 64 + lane) * 33;
        #pragma unroll
        for (int i = 0; i < 16; i++) { dst[i] = o0[i]; dst[16 + i] = o1[i]; }
        lex[w * 64 + lane] = l;
    }
    __syncthreads();
    if (part == 0) {
        const float* src = Oex + (w * 64 + lane) * 33;
        #pragma unroll
        for (int i = 0; i < 16; i++) { o0[i] += src[i]; o1[i] += src[16 + i]; }
        l += lex[w * 64 + lane];
        float lother = __int_as_float(__builtin_amdgcn_ds_bpermute(paddr, __float_as_int(l)));
        float inv = 1.0f / (l + lother);
        const int b = bh >> 4, h = bh & 15;
        __hip_bfloat16* yp = y + ((size_t)(b * TT + qlane)) * DDim + h * DHEAD;
        #pragma unroll
        for (int gg = 0; gg < 4; gg++) {
            int d0 = 8 * gg + 4 * hi;
            uint2 pa, pb;
            pa.x = pk2(o0[4*gg+0] * inv, o0[4*gg+1] * inv);
            pa.y = pk2(o0[4*gg+2] * inv, o0[4*gg+3] * inv);
            pb.x = pk2(o1[4*gg+0] * inv, o1[4*gg+1] * inv);
            pb.y = pk2(o1[4*gg+2] * inv, o1[4*gg+3] * inv);
            *(uint2*)&yp[d0] = pa;
            *(uint2*)&yp[32 + d0] = pb;
        }
    }
}

extern "C" void kernel_launch(void* const* d_in, const int* in_sizes, int n_in,
                              void* d_out, int out_size, void* d_ws, size_t ws_size,
                              hipStream_t stream) {
    const float* x      = (const float*)d_in[0];
    const float* W_abq  = (const float*)d_in[1];
    const float* W_abkv = (const float*)d_in[2];
    const float* W_o    = (const float*)d_in[3];
    float* out = (float*)d_out;

    char* ws = (char*)d_ws;
    __hip_bfloat16* xb   = (__hip_bfloat16*)ws;  ws += (size_t)4194304 * 2;
    __hip_bfloat16* wqk  = (__hip_bfloat16*)ws;  ws += (size_t)NQK * 1024 * 2;
    __hip_bfloat16* wo_b = (__hip_bfloat16*)ws;  ws += (size_t)1048576 * 2;
    __hip_bfloat16* abqkv = (__hip_bfloat16*)ws; ws += (size_t)4096 * NQK * 2;
    __hip_bfloat16* qb = (__hip_bfloat16*)ws;    ws += (size_t)4194304 * 2;
    __hip_bfloat16* kb = (__hip_bfloat16*)ws;    ws += (size_t)4194304 * 2;
    __hip_bfloat16* vT = (__hip_bfloat16*)ws;    ws += (size_t)4194304 * 2;
    __hip_bfloat16* yb = (__hip_bfloat16*)ws;    ws += (size_t)4194304 * 2;

    cvt_all<<<dim3(5920), dim3(256), 0, stream>>>(x, W_abq, W_abkv, W_o, xb, wqk, wo_b);
    gemm_bf16<true><<<dim3(7, 64), dim3(256), 0, stream>>>(xb, wqk, abqkv, 4096, NQK, 1024);
    qkv_kernel<<<dim3(1024), dim3(256), 0, stream>>>(abqkv, qb, kb, vT);
    flash_mfma<<<dim3(512), dim3(512), 0, stream>>>(qb, kb, vT, yb);
    gemm_bf16<false><<<dim3(8, 64), dim3(256), 0, stream>>>(yb, wo_b, out, 4096, 1024, 1024);
}